// Round 13
// baseline (366.975 us; speedup 1.0000x reference)
//
#include <hip/hip_runtime.h>
#include <hip/hip_bf16.h>

#define NN 2048
#define NE 65536
#define NG 32
#define CIN 128
#define CED 32
#define CLAT 64
#define CFA 16
#define CNB 5
#define NL 5

#define OFF_AT (NN * CLAT)
#define OFF_B  (NN * CLAT + NN * CFA)

typedef __attribute__((ext_vector_type(8))) short bf16x8;
typedef __attribute__((ext_vector_type(4))) float f32x4;

__device__ __forceinline__ float silu_f(float v) { return v / (1.0f + __expf(-v)); }
__device__ __forceinline__ short f2bs(float v) {
    __hip_bfloat16 h = __float2bfloat16(v);
    return *reinterpret_cast<short*>(&h);
}
__device__ __forceinline__ float bs2f(short s) {
    return __bfloat162float(*reinterpret_cast<__hip_bfloat16*>(&s));
}
__device__ __forceinline__ unsigned pack2(float a, float b) {
    return ((unsigned)(unsigned short)f2bs(b) << 16) | (unsigned short)f2bs(a);
}

struct KArgs {
    const float *x, *t, *z;
    const int *jj, *ii;           // edge_index rows 0 (j) and 1 (i)
    const float *ea;
    const int *batch, *beg;
    const float *Wt_a, *bt_a, *Wt_b, *bt_b, *W_atom, *b_atom, *W_bond, *b_bond;
    const float *W_lat, *b_lat, *W_at, *b_at, *W_bt, *b_bt;
    const float *Wmsg, *bmsg, *Wnode, *bnode, *Wedge, *bedge;
    const float *Wsh, *bsh, *Wbm, *bbm, *Wbl, *bbl, *Wal, *bal;
    float *s, *e, *agg;
    int *cnt, *rowpos, *invp, *i_s, *j_s;
    float *s2, *U, *V, *P, *Q;
    int *map;
    short *s_bf, *e_bf;
    short *Wpn, *Wpsh, *Wpal, *Wpbm, *Wproj, *W3m, *We3;
    float *out;
};

// ---------------- phase: pack weights (strided; bound 245760) ----------------------------------
__device__ __forceinline__ void phase_pack(const KArgs& a, int start, int stride)
{
    for (int idx = start; idx < 6 * 4 * 20 * 64 * 8; idx += stride) {
        int j = idx & 7, t0 = idx >> 3, lane = t0 & 63, tt = t0 >> 6;
        int kq = (lane >> 4) * 8 + j, n16 = lane & 15;
        if (idx < NL * 8 * 8 * 64 * 8) { // Wnode K=256 N=128
            int nt = tt & 7, kt = (tt >> 3) & 7, l = tt >> 6;
            a.Wpn[idx] = f2bs(a.Wnode[((size_t)l * 256 + kt * 32 + kq) * CIN + nt * 16 + n16]);
        }
        if (idx < 4 * 8 * 64 * 8) { // Wsh K=128 N=128
            int nt = tt & 7, kt = tt >> 3;
            a.Wpsh[idx] = f2bs(a.Wsh[(size_t)(kt * 32 + kq) * CIN + nt * 16 + n16]);
        }
        if (idx < 4 * 5 * 64 * 8) { // Wal K=128 N=80
            int nt = tt % 5, kt = tt / 5;
            a.Wpal[idx] = f2bs(a.Wal[(size_t)(kt * 32 + kq) * 80 + nt * 16 + n16]);
        }
        if (idx < 8 * 64 * 8) { // Wbm K=32 N=128
            int nt = tt & 7;
            a.Wpbm[idx] = f2bs(a.Wbm[(size_t)kq * CIN + nt * 16 + n16]);
        }
        { // Wproj: 6 slots, K=128, N=320 (bound == loop bound)
            int nt = tt % 20; int t2 = tt / 20; int kt = t2 & 3; int slot = t2 >> 2;
            int k = kt * 32 + kq;
            float v;
            if (nt < 16) {
                int msgl = slot % 5;
                int srcK = (nt < 8) ? k : 128 + k;
                int col = (nt & 7) * 16 + n16;
                v = a.Wmsg[((size_t)msgl * 288 + srcK) * CIN + col];
            } else {
                int edgel = (slot == 0) ? 0 : slot - 1;
                int srcK = (nt < 18) ? k : 128 + k;
                int col = (nt & 1) * 16 + n16;
                v = a.Wedge[((size_t)edgel * 288 + srcK) * CED + col];
            }
            a.Wproj[idx] = f2bs(v);
        }
        if (idx < NL * 8 * 64 * 8) { // W3m: Wmsg rows 256..287, K=32 N=128
            int nt = tt & 7, l = tt >> 3;
            a.W3m[idx] = f2bs(a.Wmsg[((size_t)l * 288 + 256 + kq) * CIN + nt * 16 + n16]);
        }
        if (idx < NL * 2 * 64 * 8) { // We3: Wedge rows 256..287, K=32 N=32
            int nt = tt & 1, l = tt >> 1;
            a.We3[idx] = f2bs(a.Wedge[((size_t)l * 288 + 256 + kq) * CED + nt * 16 + n16]);
        }
    }
}

// ---------------- phase: init s (16 nodes per tile) --------------------------------------------
__device__ __forceinline__ void phase_init_s(const KArgs& a, char* smem, int tile, int tid)
{
    float* xs  = (float*)smem;            // 16*16
    float* zs  = (float*)(smem + 1024);   // 16*64
    float* tmp = (float*)(smem + 5120);   // 16*128
    float* tv  = (float*)(smem + 13312);  // 16
    int nb0 = tile * 16;
    int c = tid & 127, h = tid >> 7;
    if (tid < 16 * CFA / 4) ((float4*)xs)[tid] = ((const float4*)a.x)[nb0 * (CFA / 4) + tid];
    if (tid < 16 * CLAT / 4) ((float4*)zs)[tid] = ((const float4*)a.z)[nb0 * (CLAT / 4) + tid];
    if (tid < 16) tv[tid] = a.t[a.batch[nb0 + tid]];
    __syncthreads();
    float wta = a.Wt_a[c], base0 = a.b_atom[c] + a.bt_a[c];
    float acc[8];
#pragma unroll
    for (int q = 0; q < 8; q++) acc[q] = base0 + tv[h * 8 + q] * wta;
    for (int k = 0; k < CFA; k++) {
        float w = a.W_atom[k * CIN + c];
#pragma unroll
        for (int q = 0; q < 8; q++) acc[q] += xs[(h * 8 + q) * CFA + k] * w;
    }
#pragma unroll
    for (int q = 0; q < 8; q++) tmp[(h * 8 + q) * CIN + c] = acc[q];
    __syncthreads();
    float base1 = a.b_at[c] + a.b_lat[c];
    float acc2[8];
#pragma unroll
    for (int q = 0; q < 8; q++) acc2[q] = base1;
    for (int k4 = 0; k4 < CIN / 4; k4++) {
        float w0 = a.W_at[(4 * k4 + 0) * CIN + c], w1 = a.W_at[(4 * k4 + 1) * CIN + c];
        float w2 = a.W_at[(4 * k4 + 2) * CIN + c], w3 = a.W_at[(4 * k4 + 3) * CIN + c];
#pragma unroll
        for (int q = 0; q < 8; q++) {
            float4 f = *(const float4*)&tmp[(h * 8 + q) * CIN + 4 * k4];
            acc2[q] += f.x * w0 + f.y * w1 + f.z * w2 + f.w * w3;
        }
    }
    for (int k4 = 0; k4 < CLAT / 4; k4++) {
        float w0 = a.W_lat[(4 * k4 + 0) * CIN + c], w1 = a.W_lat[(4 * k4 + 1) * CIN + c];
        float w2 = a.W_lat[(4 * k4 + 2) * CIN + c], w3 = a.W_lat[(4 * k4 + 3) * CIN + c];
#pragma unroll
        for (int q = 0; q < 8; q++) {
            float4 f = *(const float4*)&zs[(h * 8 + q) * CLAT + 4 * k4];
            acc2[q] += f.x * w0 + f.y * w1 + f.z * w2 + f.w * w3;
        }
    }
#pragma unroll
    for (int q = 0; q < 8; q++) {
        int nd = nb0 + h * 8 + q;
        a.s[(size_t)nd * CIN + c] = acc2[q];
        a.s_bf[(size_t)nd * CIN + c] = f2bs(acc2[q]);
    }
}

// ---------------- phase: init e tile (64 edges), sorted-order write ----------------------------
__device__ __forceinline__ void phase_init_e(const KArgs& a, char* smem, int tb, int tid)
{
    float* eas   = (float*)smem;            // 320
    float* tv    = (float*)(smem + 1280);   // 64
    int*   sp    = (int*)(smem + 1536);     // 64
    float* tmp   = (float*)(smem + 1792);   // 64*33
    float* wbt   = (float*)(smem + 10240);  // 1024
    float* wbond = (float*)(smem + 14336);  // 160
    float* cb    = (float*)(smem + 14976);
    float* wtb   = (float*)(smem + 15104);
    float* bbt2  = (float*)(smem + 15232);
    int k0 = tb * 64;
    for (int idx = tid; idx < 320; idx += 256) eas[idx] = a.ea[(size_t)k0 * 5 + idx];
    if (tid < 64) { tv[tid] = a.t[a.beg[k0 + tid]]; sp[tid] = a.invp[k0 + tid]; }
    for (int idx = tid; idx < 1024; idx += 256) wbt[idx] = a.W_bt[idx];
    if (tid < 160) wbond[tid] = a.W_bond[tid];
    if (tid < 32) { cb[tid] = a.b_bond[tid] + a.bt_b[tid]; wtb[tid] = a.Wt_b[tid]; bbt2[tid] = a.b_bt[tid]; }
    __syncthreads();
    int ch = tid & 31, eg = tid >> 5;
#pragma unroll
    for (int q = 0; q < 8; q++) {
        int le = eg * 8 + q;
        float acc = cb[ch] + tv[le] * wtb[ch];
#pragma unroll
        for (int bb = 0; bb < CNB; bb++) acc += eas[le * 5 + bb] * wbond[bb * 32 + ch];
        tmp[le * 33 + ch] = acc;
    }
    __syncthreads();
#pragma unroll
    for (int q = 0; q < 8; q++) {
        int le = eg * 8 + q;
        float acc2 = bbt2[ch];
        for (int d = 0; d < 32; d++) acc2 += tmp[le * 33 + d] * wbt[d * 32 + ch];
        size_t ix = (size_t)sp[le] * CED + ch;
        a.e[ix] = acc2;
        a.e_bf[ix] = f2bs(acc2);
        if (ch == 0) {
            int k = k0 + le;
            atomicMax(&a.map[(size_t)a.jj[k] * NN + a.ii[k]], k); // numpy last-write-wins
        }
    }
}

// ---------------- phase: node update + projections (8 nodes per tile, 256 blocks) --------------
// MFMA tiles are 16-row; rows 8-15 compute garbage and all stores are guarded by row<8.
__device__ __forceinline__ void phase_node_proj(
    const KArgs& a, char* smem, int tile, int tid, bool DO_NODE,
    const short* Wpn_l, const float* bnode_l, const short* Wproj_slot)
{
    short* feat  = (short*)smem;            // 16*264 alloc (8 populated)
    short* feat2 = (short*)(smem + 8448);   // 16*136 alloc (8 populated)
    int nb0 = tile * 8;
    int lane = tid & 63, w = tid >> 6;
    int quad = lane >> 4, n16 = lane & 15;

    if (DO_NODE) {
        if (tid < 128) { int kl = tid >> 4, c = tid & 15;
          *(uint4*)&feat[kl * 264 + c * 8] = ((const uint4*)a.s_bf)[(size_t)(nb0 + kl) * 16 + c]; }
        { // agg: 8 rows x 32 float4 = 256, one per thread; zero after read
            int kl = tid >> 5, c = tid & 31;
            size_t gix = (size_t)(nb0 + kl) * 32 + c;
            float4 v = ((const float4*)a.agg)[gix];
            ((float4*)a.agg)[gix] = (float4){0.f, 0.f, 0.f, 0.f};
            uint2 p; p.x = pack2(v.x, v.y); p.y = pack2(v.z, v.w);
            *(uint2*)&feat[kl * 264 + 128 + 4 * c] = p;
        }
        __syncthreads();
        f32x4 acc[2];
        acc[0] = (f32x4){0.f, 0.f, 0.f, 0.f};
        acc[1] = (f32x4){0.f, 0.f, 0.f, 0.f};
        const short* fbase = feat + n16 * 264 + quad * 8;
#pragma unroll
        for (int kt = 0; kt < 8; kt++) {
            bf16x8 av = *(const bf16x8*)(fbase + kt * 32);
#pragma unroll
            for (int n2 = 0; n2 < 2; n2++) {
                int nt = w * 2 + n2;
                bf16x8 b = *(const bf16x8*)(Wpn_l + ((size_t)(kt * 8 + nt) * 64 + lane) * 8);
                acc[n2] = __builtin_amdgcn_mfma_f32_16x16x32_bf16(av, b, acc[n2], 0, 0, 0);
            }
        }
#pragma unroll
        for (int n2 = 0; n2 < 2; n2++) {
            int col = (w * 2 + n2) * 16 + n16;
            float bb = bnode_l[col];
#pragma unroll
            for (int r = 0; r < 4; r++) {
                int row = quad * 4 + r;
                if (row < 8) {
                    size_t ix = (size_t)(nb0 + row) * CIN + col;
                    float v = a.s[ix] + silu_f(acc[n2][r] + bb);
                    a.s[ix] = v;
                    short bv = f2bs(v);
                    a.s_bf[ix] = bv;
                    feat2[row * 136 + col] = bv;
                }
            }
        }
        __syncthreads();
    } else {
        if (tid < 128) { int kl = tid >> 4, c = tid & 15;
          *(uint4*)&feat2[kl * 136 + c * 8] = ((const uint4*)a.s_bf)[(size_t)(nb0 + kl) * 16 + c]; }
        __syncthreads();
    }

    f32x4 accp[5];
#pragma unroll
    for (int t2 = 0; t2 < 5; t2++) accp[t2] = (f32x4){0.f, 0.f, 0.f, 0.f};
    const short* abase = feat2 + n16 * 136 + quad * 8;
#pragma unroll
    for (int kt = 0; kt < 4; kt++) {
        bf16x8 av = *(const bf16x8*)(abase + kt * 32);
#pragma unroll
        for (int n5 = 0; n5 < 5; n5++) {
            int nt = w * 5 + n5;
            bf16x8 b = *(const bf16x8*)(Wproj_slot + ((size_t)(kt * 20 + nt) * 64 + lane) * 8);
            accp[n5] = __builtin_amdgcn_mfma_f32_16x16x32_bf16(av, b, accp[n5], 0, 0, 0);
        }
    }
    if (quad < 2) { // rows 0-7 only
#pragma unroll
        for (int n5 = 0; n5 < 5; n5++) {
            int nt = w * 5 + n5;
#pragma unroll
            for (int r = 0; r < 4; r++) {
                int node = nb0 + quad * 4 + r;
                float v = accp[n5][r];
                if (nt < 8)       a.U[(size_t)node * CIN + nt * 16 + n16] = v;
                else if (nt < 16) a.V[(size_t)node * CIN + (nt - 8) * 16 + n16] = v;
                else if (nt < 18) a.P[(size_t)node * CED + (nt - 16) * 16 + n16] = v;
                else              a.Q[(size_t)node * CED + (nt - 18) * 16 + n16] = v;
            }
        }
    }
}

// ---------------- phase: per-edge tile (64 sorted edges); bf16 uv/pq ---------------------------
// LDS: feat_e 5120 | uv_bf 17408 | pq_bf 5120 | sii 256 | sjj 256 = 28160 B -> 5 blocks/CU
__device__ __forceinline__ void phase_em(
    const KArgs& a, char* smem, int tb, int tid, bool DO_EDGE, bool DO_MSG,
    const short* We3p, const float* bedge_l, const short* W3mp, const float* bmsg_l)
{
    short* feat_e = (short*)smem;             // 64*40 bf16
    short* uv_bf  = (short*)(smem + 5120);    // 64*136 bf16 (U[i]+V[j]; then m values)
    short* pq_bf  = (short*)(smem + 22528);   // 64*40 bf16 (P[i]+Q[j])
    int*   sii    = (int*)(smem + 27648);     // 64
    int*   sjj    = (int*)(smem + 27904);     // 64
    int e0 = tb * 64;
    if (tid < 64) sii[tid] = a.i_s[e0 + tid];
    else if (tid < 128) sjj[tid - 64] = a.j_s[e0 + tid - 64];
    __syncthreads();
    { int kl = tid >> 2, c = tid & 3;
      uint4 v = ((const uint4*)a.e_bf)[(size_t)e0 * 4 + tid];
      *(uint4*)&feat_e[kl * 40 + c * 8] = v; }
    if (DO_EDGE) {
        for (int idx = tid; idx < 64 * 8; idx += 256) {
            int kl = idx >> 3, c = idx & 7;
            float4 av = ((const float4*)a.P)[(size_t)sii[kl] * 8 + c];
            float4 bv = ((const float4*)a.Q)[(size_t)sjj[kl] * 8 + c];
            uint2 p; p.x = pack2(av.x + bv.x, av.y + bv.y); p.y = pack2(av.z + bv.z, av.w + bv.w);
            *(uint2*)&pq_bf[kl * 40 + 4 * c] = p;
        }
    }
    if (DO_MSG) {
        for (int idx = tid; idx < 64 * 32; idx += 256) {
            int kl = idx >> 5, c = idx & 31;
            float4 av = ((const float4*)a.U)[(size_t)sii[kl] * 32 + c];
            float4 bv = ((const float4*)a.V)[(size_t)sjj[kl] * 32 + c];
            uint2 p; p.x = pack2(av.x + bv.x, av.y + bv.y); p.y = pack2(av.z + bv.z, av.w + bv.w);
            *(uint2*)&uv_bf[kl * 136 + 4 * c] = p;
        }
    }
    __syncthreads();
    int lane = tid & 63, w = tid >> 6;
    int quad = lane >> 4, n16 = lane & 15;
    const short* abase = feat_e + (w * 16 + n16) * 40 + quad * 8;
    bf16x8 av = *(const bf16x8*)abase;

    if (DO_EDGE) {
        f32x4 acc_e[2];
        acc_e[0] = (f32x4){0.f, 0.f, 0.f, 0.f};
        acc_e[1] = (f32x4){0.f, 0.f, 0.f, 0.f};
#pragma unroll
        for (int nt = 0; nt < 2; nt++) {
            bf16x8 b = *(const bf16x8*)(We3p + ((size_t)(nt * 64 + lane)) * 8);
            acc_e[nt] = __builtin_amdgcn_mfma_f32_16x16x32_bf16(av, b, acc_e[nt], 0, 0, 0);
        }
#pragma unroll
        for (int nt = 0; nt < 2; nt++) {
            int ch = nt * 16 + n16;
            float bb = bedge_l[ch];
#pragma unroll
            for (int r = 0; r < 4; r++) {
                int el = w * 16 + quad * 4 + r;
                size_t ix = (size_t)(e0 + el) * CED + ch;
                float v = a.e[ix] + silu_f(acc_e[nt][r] + bb + bs2f(pq_bf[el * 40 + ch]));
                a.e[ix] = v;
                short bv = f2bs(v);
                a.e_bf[ix] = bv;
                feat_e[el * 40 + ch] = bv;
            }
        }
        av = *(const bf16x8*)abase; // re-read own-wave patched row
    }

    if (DO_MSG) {
        f32x4 acc_m[8];
#pragma unroll
        for (int t2 = 0; t2 < 8; t2++) acc_m[t2] = (f32x4){0.f, 0.f, 0.f, 0.f};
#pragma unroll
        for (int nt = 0; nt < 8; nt++) {
            bf16x8 b = *(const bf16x8*)(W3mp + ((size_t)(nt * 64 + lane)) * 8);
            acc_m[nt] = __builtin_amdgcn_mfma_f32_16x16x32_bf16(av, b, acc_m[nt], 0, 0, 0);
        }
#pragma unroll
        for (int nt = 0; nt < 8; nt++) {
            int ch = nt * 16 + n16;
            float bb = bmsg_l[ch];
#pragma unroll
            for (int r = 0; r < 4; r++) {
                int el = w * 16 + quad * 4 + r;
                int lix = el * 136 + ch;
                float m = silu_f(acc_m[nt][r] + bb + bs2f(uv_bf[lix])); // (el,ch) owner thread
                uv_bf[lix] = f2bs(m);
            }
        }
        __syncthreads();
        if (tid < 128) { // group-reduce by sorted target; fp32 running sum
            int c = tid;
            float run = 0.f;
            int cur = sii[0];
            for (int r = 0; r < 64; r++) {
                int tg = sii[r];
                if (tg != cur) { atomicAdd(&a.agg[(size_t)cur * CIN + c], run); run = 0.f; cur = tg; }
                run += bs2f(uv_bf[r * 136 + c]);
            }
            atomicAdd(&a.agg[(size_t)cur * CIN + c], run);
        }
    }
}

// ---------------- phase: post node (8 nodes per tile, 256 blocks) ------------------------------
__device__ __forceinline__ void phase_post_node(const KArgs& a, char* smem, int tile, int tid)
{
    short* feat    = (short*)smem;           // 16*136 alloc (8 populated)
    short* feat_s2 = (short*)(smem + 4352);  // 16*136 alloc (8 populated)
    int nb0 = tile * 8;
    int lane = tid & 63, w = tid >> 6;
    int quad = lane >> 4, n16 = lane & 15;
    if (tid < 128) { int kl = tid >> 4, c = tid & 15;
      *(uint4*)&feat[kl * 136 + c * 8] = ((const uint4*)a.s_bf)[(size_t)(nb0 + kl) * 16 + c]; }
    __syncthreads();
    const short* fbase = feat + n16 * 136 + quad * 8;
    f32x4 acc[2];
    acc[0] = (f32x4){0.f, 0.f, 0.f, 0.f};
    acc[1] = (f32x4){0.f, 0.f, 0.f, 0.f};
#pragma unroll
    for (int kt = 0; kt < 4; kt++) {
        bf16x8 av = *(const bf16x8*)(fbase + kt * 32);
#pragma unroll
        for (int n2 = 0; n2 < 2; n2++) {
            int nt = w * 2 + n2;
            bf16x8 b = *(const bf16x8*)(a.Wpsh + ((size_t)(kt * 8 + nt) * 64 + lane) * 8);
            acc[n2] = __builtin_amdgcn_mfma_f32_16x16x32_bf16(av, b, acc[n2], 0, 0, 0);
        }
    }
#pragma unroll
    for (int n2 = 0; n2 < 2; n2++) {
        int col = (w * 2 + n2) * 16 + n16;
        float bb = a.bsh[col];
#pragma unroll
        for (int r = 0; r < 4; r++) {
            int row = quad * 4 + r;
            if (row < 8) {
                float v = silu_f(acc[n2][r] + bb);
                a.s2[(size_t)(nb0 + row) * CIN + col] = v;
                feat_s2[row * 136 + col] = f2bs(v);
            }
        }
    }
    __syncthreads();
    const short* abase = feat_s2 + n16 * 136 + quad * 8;
    f32x4 acca[2];
    acca[0] = (f32x4){0.f, 0.f, 0.f, 0.f};
    acca[1] = (f32x4){0.f, 0.f, 0.f, 0.f};
    int nAl = (w == 0) ? 2 : 1;
    int ntl[2] = {w, 4};
#pragma unroll
    for (int kt = 0; kt < 4; kt++) {
        bf16x8 av = *(const bf16x8*)(abase + kt * 32);
#pragma unroll
        for (int q = 0; q < 2; q++) {
            if (q < nAl) {
                bf16x8 b = *(const bf16x8*)(a.Wpal + ((size_t)(kt * 5 + ntl[q]) * 64 + lane) * 8);
                acca[q] = __builtin_amdgcn_mfma_f32_16x16x32_bf16(av, b, acca[q], 0, 0, 0);
            }
        }
    }
    if (quad < 2) { // rows 0-7 only
#pragma unroll
        for (int q = 0; q < 2; q++) {
            if (q < nAl) {
                int col = ntl[q] * 16 + n16;
                float bb = a.bal[col];
#pragma unroll
                for (int r = 0; r < 4; r++) {
                    int node = nb0 + quad * 4 + r;
                    float v = acca[q][r] + bb;
                    if (col < CFA) a.out[OFF_AT + node * CFA + col] = v;
                    else           a.out[(size_t)node * CLAT + (col - CFA)] = v;
                }
            }
        }
    }
}

// ---------------- phase: post edge tile (64 edges, original order); bf16 sbias/fshT ------------
// LDS: esym 5120 | shared region 17408 (sbias_bf [64][136] -> fshT_bf [128][68]) | idx 1024 = 23552
__device__ __forceinline__ void phase_post_edge(const KArgs& a, char* smem, int tb, int tid)
{
    short* esym = (short*)smem;              // 64*40
    short* sb   = (short*)(smem + 5120);     // shared region
    int* sii = (int*)(smem + 22528);
    int* sjj = (int*)(smem + 22784);
    int* skf = (int*)(smem + 23040);
    int* skb = (int*)(smem + 23296);
    int e0 = tb * 64;
    if (tid < 64) sii[tid] = a.ii[e0 + tid];
    else if (tid < 128) sjj[tid - 64] = a.jj[e0 + tid - 64];
    __syncthreads();
    if (tid < 64) skf[tid] = a.invp[a.map[(size_t)sjj[tid] * NN + sii[tid]]];
    else if (tid < 128) {
        int m = a.map[(size_t)sii[tid - 64] * NN + sjj[tid - 64]];
        skb[tid - 64] = (m >= 0) ? a.invp[m] : -1;
    }
    __syncthreads();
    for (int idx = tid; idx < 64 * 8; idx += 256) {
        int kl = idx >> 3, c = idx & 7;
        float4 av = ((const float4*)a.e)[(size_t)skf[kl] * 8 + c];
        int kb = skb[kl];
        float4 bv = {0.f, 0.f, 0.f, 0.f};
        if (kb >= 0) bv = ((const float4*)a.e)[(size_t)kb * 8 + c];
        uint2 p; p.x = pack2(0.5f * (av.x + bv.x), 0.5f * (av.y + bv.y));
        p.y = pack2(0.5f * (av.z + bv.z), 0.5f * (av.w + bv.w));
        *(uint2*)&esym[kl * 40 + 4 * c] = p;
    }
    for (int idx = tid; idx < 64 * 32; idx += 256) { // sbias_bf rows (stride 136)
        int kl = idx >> 5, c = idx & 31;
        float4 av = ((const float4*)a.s2)[(size_t)sii[kl] * 32 + c];
        float4 bv = ((const float4*)a.s2)[(size_t)sjj[kl] * 32 + c];
        uint2 p; p.x = pack2(av.x + bv.x, av.y + bv.y); p.y = pack2(av.z + bv.z, av.w + bv.w);
        *(uint2*)&sb[kl * 136 + 4 * c] = p;
    }
    __syncthreads();
    int lane = tid & 63, w = tid >> 6;
    int quad = lane >> 4, n16 = lane & 15;
    bf16x8 av = *(const bf16x8*)(esym + (w * 16 + n16) * 40 + quad * 8);
    f32x4 acc[8];
#pragma unroll
    for (int nt = 0; nt < 8; nt++) {
        bf16x8 b = *(const bf16x8*)(a.Wpbm + ((size_t)nt * 64 + lane) * 8);
        f32x4 zero = {0.f, 0.f, 0.f, 0.f};
        acc[nt] = __builtin_amdgcn_mfma_f32_16x16x32_bf16(av, b, zero, 0, 0, 0);
    }
    float f[8][4];
#pragma unroll
    for (int nt = 0; nt < 8; nt++) {
        int col = nt * 16 + n16;
        float bb = a.bbm[col];
#pragma unroll
        for (int r = 0; r < 4; r++) {
            int row = w * 16 + quad * 4 + r;
            f[nt][r] = silu_f(acc[nt][r] + bb + bs2f(sb[row * 136 + col]));
        }
    }
    __syncthreads(); // all sbias reads done; reuse region as fshT_bf [128][68]
#pragma unroll
    for (int nt = 0; nt < 8; nt++) {
        int col = nt * 16 + n16;
#pragma unroll
        for (int r = 0; r < 4; r++) {
            int row = w * 16 + quad * 4 + r;
            sb[col * 68 + row] = f2bs(f[nt][r]);
        }
    }
    __syncthreads();
    for (int idx = tid; idx < 64 * CNB; idx += 256) {
        int kl = idx / CNB, b = idx - kl * CNB;
        float acc3 = a.bbl[b];
        for (int d = 0; d < CIN; d++) acc3 += bs2f(sb[d * 68 + kl]) * a.Wbl[d * CNB + b];
        a.out[OFF_B + (size_t)(e0 + kl) * CNB + b] = acc3;
    }
}

// ---------------- kernels ----------------------------------------------------------------------
__global__ __launch_bounds__(256) void k_prologue(KArgs a)
{
    __shared__ __align__(16) char smem[13440];
    int b = blockIdx.x, tid = threadIdx.x;
    if (b < 960) phase_pack(a, b * 256 + tid, 960 * 256);
    else if (b < 1088) phase_init_s(a, smem, b - 960, tid);
    else {
        int base = (b - 1088) * 1024;
#pragma unroll
        for (int q = 0; q < 4; q++) atomicAdd(&a.cnt[a.ii[base + q * 256 + tid]], 1);
    }
}
__global__ __launch_bounds__(256) void k_prefix(KArgs a)
{
    __shared__ int part[256];
    int tid = threadIdx.x;
    int loc[8], sum = 0;
#pragma unroll
    for (int q = 0; q < 8; q++) { loc[q] = a.cnt[tid * 8 + q]; sum += loc[q]; }
    part[tid] = sum;
    __syncthreads();
    if (tid == 0) { int r = 0; for (int i = 0; i < 256; i++) { int v = part[i]; part[i] = r; r += v; } }
    __syncthreads();
    int r = part[tid];
#pragma unroll
    for (int q = 0; q < 8; q++) { a.rowpos[tid * 8 + q] = r; r += loc[q]; }
}
__global__ void k_perm(KArgs a)
{
    int k = blockIdx.x * 256 + threadIdx.x;
    int iv = a.ii[k];
    int p = atomicAdd(&a.rowpos[iv], 1);
    a.invp[k] = p;
    a.i_s[p] = iv;
    a.j_s[p] = a.jj[k];
}
__global__ __launch_bounds__(256) void k_init_e(KArgs a)
{
    __shared__ __align__(16) char smem[15360];
    phase_init_e(a, smem, blockIdx.x, threadIdx.x);
}
__global__ __launch_bounds__(256) void k_node_proj(KArgs a, int donode, const short* Wpn_l,
                                                   const float* bnode_l, const short* Wproj_slot)
{
    __shared__ __align__(16) char smem[12800];
    phase_node_proj(a, smem, blockIdx.x, threadIdx.x, donode != 0, Wpn_l, bnode_l, Wproj_slot);
}
__global__ __launch_bounds__(256) void k_em(KArgs a, int de, int dm, const short* We3p,
                                            const float* bedge_l, const short* W3mp, const float* bmsg_l)
{
    __shared__ __align__(16) char smem[28160]; // 5 blocks/CU
    phase_em(a, smem, blockIdx.x, threadIdx.x, de != 0, dm != 0, We3p, bedge_l, W3mp, bmsg_l);
}
__global__ __launch_bounds__(256) void k_post_node(KArgs a)
{
    __shared__ __align__(16) char smem[8704];
    phase_post_node(a, smem, blockIdx.x, threadIdx.x);
}
__global__ __launch_bounds__(256) void k_post_edge(KArgs a)
{
    __shared__ __align__(16) char smem[23552]; // 6 blocks/CU
    phase_post_edge(a, smem, blockIdx.x, threadIdx.x);
}

extern "C" void kernel_launch(void* const* d_in, const int* in_sizes, int n_in,
                              void* d_out, int out_size, void* d_ws, size_t ws_size,
                              hipStream_t stream) {
    KArgs a;
    a.x      = (const float*)d_in[0];
    a.t      = (const float*)d_in[1];
    a.z      = (const float*)d_in[2];
    const int* eidx = (const int*)d_in[3];
    a.jj     = eidx;        // edge_index[0] = j
    a.ii     = eidx + NE;   // edge_index[1] = i
    a.ea     = (const float*)d_in[4];
    a.batch  = (const int*)d_in[5];
    a.beg    = (const int*)d_in[6];
    a.Wt_a   = (const float*)d_in[7];
    a.bt_a   = (const float*)d_in[8];
    a.Wt_b   = (const float*)d_in[9];
    a.bt_b   = (const float*)d_in[10];
    a.W_atom = (const float*)d_in[11];
    a.b_atom = (const float*)d_in[12];
    a.W_bond = (const float*)d_in[13];
    a.b_bond = (const float*)d_in[14];
    a.W_lat  = (const float*)d_in[15];
    a.b_lat  = (const float*)d_in[16];
    a.W_at   = (const float*)d_in[17];
    a.b_at   = (const float*)d_in[18];
    a.W_bt   = (const float*)d_in[19];
    a.b_bt   = (const float*)d_in[20];
    a.Wmsg   = (const float*)d_in[21];
    a.bmsg   = (const float*)d_in[22];
    a.Wnode  = (const float*)d_in[23];
    a.bnode  = (const float*)d_in[24];
    a.Wedge  = (const float*)d_in[25];
    a.bedge  = (const float*)d_in[26];
    a.Wsh    = (const float*)d_in[27];
    a.bsh    = (const float*)d_in[28];
    a.Wbm    = (const float*)d_in[29];
    a.bbm    = (const float*)d_in[30];
    a.Wbl    = (const float*)d_in[31];
    a.bbl    = (const float*)d_in[32];
    a.Wal    = (const float*)d_in[33];
    a.bal    = (const float*)d_in[34];

    a.s      = (float*)d_ws;
    a.e      = a.s + (size_t)NN * CIN;
    a.agg    = a.e + (size_t)NE * CED;
    a.cnt    = (int*)(a.agg + (size_t)NN * CIN);
    a.rowpos = a.cnt + NN;
    a.invp   = a.rowpos + NN;
    a.i_s    = a.invp + NE;
    a.j_s    = a.i_s + NE;
    a.s2     = (float*)(a.j_s + NE);
    a.U      = a.s2 + (size_t)NN * CIN;
    a.V      = a.U + (size_t)NN * CIN;
    a.P      = a.V + (size_t)NN * CIN;
    a.Q      = a.P + (size_t)NN * CED;
    a.map    = (int*)(a.Q + (size_t)NN * CED);
    a.s_bf   = (short*)(a.map + (size_t)NN * NN);
    a.e_bf   = a.s_bf + (size_t)NN * CIN;
    a.Wpn    = a.e_bf + (size_t)NE * CED;
    a.Wpsh   = a.Wpn + (size_t)NL * 8 * 8 * 64 * 8;
    a.Wpal   = a.Wpsh + (size_t)4 * 8 * 64 * 8;
    a.Wpbm   = a.Wpal + (size_t)4 * 5 * 64 * 8;
    a.Wproj  = a.Wpbm + (size_t)8 * 64 * 8;
    a.W3m    = a.Wproj + (size_t)6 * 4 * 20 * 64 * 8;
    a.We3    = a.W3m + (size_t)NL * 8 * 64 * 8;
    a.out    = (float*)d_out;

    hipMemsetAsync(a.map, 0xFF, (size_t)NN * NN * sizeof(int), stream);
    hipMemsetAsync(a.agg, 0, ((size_t)NN * CIN + NN) * sizeof(float), stream); // agg + cnt

    k_prologue<<<1152, 256, 0, stream>>>(a);
    k_prefix<<<1, 256, 0, stream>>>(a);
    k_perm<<<NE / 256, 256, 0, stream>>>(a);
    k_init_e<<<NE / 64, 256, 0, stream>>>(a);
    k_node_proj<<<NN / 8, 256, 0, stream>>>(a, 0, nullptr, nullptr, a.Wproj);
    k_em<<<NE / 64, 256, 0, stream>>>(a, 0, 1, nullptr, nullptr, a.W3m, a.bmsg);
    for (int l = 0; l < NL; l++) {
        k_node_proj<<<NN / 8, 256, 0, stream>>>(a, 1,
            a.Wpn + (size_t)l * 8 * 8 * 64 * 8, a.bnode + l * CIN,
            a.Wproj + (size_t)(l + 1) * 4 * 20 * 64 * 8);
        int dm = (l < NL - 1) ? 1 : 0;
        k_em<<<NE / 64, 256, 0, stream>>>(a, 1, dm,
            a.We3 + (size_t)l * 2 * 64 * 8, a.bedge + l * CED,
            dm ? a.W3m + (size_t)(l + 1) * 8 * 64 * 8 : a.W3m,
            dm ? a.bmsg + (l + 1) * CIN : a.bmsg);
    }
    k_post_node<<<NN / 8, 256, 0, stream>>>(a);
    k_post_edge<<<NE / 64, 256, 0, stream>>>(a);
}

// Round 14
// 356.250 us; speedup vs baseline: 1.0301x; 1.0301x over previous
//
#include <hip/hip_runtime.h>
#include <hip/hip_bf16.h>

#define NN 2048
#define NE 65536
#define NG 32
#define CIN 128
#define CED 32
#define CLAT 64
#define CFA 16
#define CNB 5
#define NL 5

#define OFF_AT (NN * CLAT)
#define OFF_B  (NN * CLAT + NN * CFA)

typedef __attribute__((ext_vector_type(8))) short bf16x8;
typedef __attribute__((ext_vector_type(4))) float f32x4;

__device__ __forceinline__ float silu_f(float v) { return v / (1.0f + __expf(-v)); }
__device__ __forceinline__ short f2bs(float v) {
    __hip_bfloat16 h = __float2bfloat16(v);
    return *reinterpret_cast<short*>(&h);
}
__device__ __forceinline__ float bs2f(short s) {
    return __bfloat162float(*reinterpret_cast<__hip_bfloat16*>(&s));
}
__device__ __forceinline__ unsigned pack2(float a, float b) {
    return ((unsigned)(unsigned short)f2bs(b) << 16) | (unsigned short)f2bs(a);
}

struct KArgs {
    const float *x, *t, *z;
    const int *jj, *ii;           // edge_index rows 0 (j) and 1 (i)
    const float *ea;
    const int *batch, *beg;
    const float *Wt_a, *bt_a, *Wt_b, *bt_b, *W_atom, *b_atom, *W_bond, *b_bond;
    const float *W_lat, *b_lat, *W_at, *b_at, *W_bt, *b_bt;
    const float *Wmsg, *bmsg, *Wnode, *bnode, *Wedge, *bedge;
    const float *Wsh, *bsh, *Wbm, *bbm, *Wbl, *bbl, *Wal, *bal;
    float *s, *e, *agg;
    int *cnt, *rowpos, *invp, *i_s, *j_s;
    float *s2, *U, *V, *P, *Q;
    int *map;
    short *s_bf, *e_bf;
    short *Wpn, *Wpsh, *Wpal, *Wpbm, *Wproj, *W3m, *We3;
    float *out;
};

// ---------------- phase: pack weights (strided; bound 245760) ----------------------------------
__device__ __forceinline__ void phase_pack(const KArgs& a, int start, int stride)
{
    for (int idx = start; idx < 6 * 4 * 20 * 64 * 8; idx += stride) {
        int j = idx & 7, t0 = idx >> 3, lane = t0 & 63, tt = t0 >> 6;
        int kq = (lane >> 4) * 8 + j, n16 = lane & 15;
        if (idx < NL * 8 * 8 * 64 * 8) { // Wnode K=256 N=128
            int nt = tt & 7, kt = (tt >> 3) & 7, l = tt >> 6;
            a.Wpn[idx] = f2bs(a.Wnode[((size_t)l * 256 + kt * 32 + kq) * CIN + nt * 16 + n16]);
        }
        if (idx < 4 * 8 * 64 * 8) { // Wsh K=128 N=128
            int nt = tt & 7, kt = tt >> 3;
            a.Wpsh[idx] = f2bs(a.Wsh[(size_t)(kt * 32 + kq) * CIN + nt * 16 + n16]);
        }
        if (idx < 4 * 5 * 64 * 8) { // Wal K=128 N=80
            int nt = tt % 5, kt = tt / 5;
            a.Wpal[idx] = f2bs(a.Wal[(size_t)(kt * 32 + kq) * 80 + nt * 16 + n16]);
        }
        if (idx < 8 * 64 * 8) { // Wbm K=32 N=128
            int nt = tt & 7;
            a.Wpbm[idx] = f2bs(a.Wbm[(size_t)kq * CIN + nt * 16 + n16]);
        }
        { // Wproj: 6 slots, K=128, N=320 (bound == loop bound)
            int nt = tt % 20; int t2 = tt / 20; int kt = t2 & 3; int slot = t2 >> 2;
            int k = kt * 32 + kq;
            float v;
            if (nt < 16) {
                int msgl = slot % 5;
                int srcK = (nt < 8) ? k : 128 + k;
                int col = (nt & 7) * 16 + n16;
                v = a.Wmsg[((size_t)msgl * 288 + srcK) * CIN + col];
            } else {
                int edgel = (slot == 0) ? 0 : slot - 1;
                int srcK = (nt < 18) ? k : 128 + k;
                int col = (nt & 1) * 16 + n16;
                v = a.Wedge[((size_t)edgel * 288 + srcK) * CED + col];
            }
            a.Wproj[idx] = f2bs(v);
        }
        if (idx < NL * 8 * 64 * 8) { // W3m: Wmsg rows 256..287, K=32 N=128
            int nt = tt & 7, l = tt >> 3;
            a.W3m[idx] = f2bs(a.Wmsg[((size_t)l * 288 + 256 + kq) * CIN + nt * 16 + n16]);
        }
        if (idx < NL * 2 * 64 * 8) { // We3: Wedge rows 256..287, K=32 N=32
            int nt = tt & 1, l = tt >> 1;
            a.We3[idx] = f2bs(a.Wedge[((size_t)l * 288 + 256 + kq) * CED + nt * 16 + n16]);
        }
    }
}

// ---------------- phase: init s (16 nodes per tile) --------------------------------------------
__device__ __forceinline__ void phase_init_s(const KArgs& a, char* smem, int tile, int tid)
{
    float* xs  = (float*)smem;            // 16*16
    float* zs  = (float*)(smem + 1024);   // 16*64
    float* tmp = (float*)(smem + 5120);   // 16*128
    float* tv  = (float*)(smem + 13312);  // 16
    int nb0 = tile * 16;
    int c = tid & 127, h = tid >> 7;
    if (tid < 16 * CFA / 4) ((float4*)xs)[tid] = ((const float4*)a.x)[nb0 * (CFA / 4) + tid];
    if (tid < 16 * CLAT / 4) ((float4*)zs)[tid] = ((const float4*)a.z)[nb0 * (CLAT / 4) + tid];
    if (tid < 16) tv[tid] = a.t[a.batch[nb0 + tid]];
    __syncthreads();
    float wta = a.Wt_a[c], base0 = a.b_atom[c] + a.bt_a[c];
    float acc[8];
#pragma unroll
    for (int q = 0; q < 8; q++) acc[q] = base0 + tv[h * 8 + q] * wta;
    for (int k = 0; k < CFA; k++) {
        float w = a.W_atom[k * CIN + c];
#pragma unroll
        for (int q = 0; q < 8; q++) acc[q] += xs[(h * 8 + q) * CFA + k] * w;
    }
#pragma unroll
    for (int q = 0; q < 8; q++) tmp[(h * 8 + q) * CIN + c] = acc[q];
    __syncthreads();
    float base1 = a.b_at[c] + a.b_lat[c];
    float acc2[8];
#pragma unroll
    for (int q = 0; q < 8; q++) acc2[q] = base1;
    for (int k4 = 0; k4 < CIN / 4; k4++) {
        float w0 = a.W_at[(4 * k4 + 0) * CIN + c], w1 = a.W_at[(4 * k4 + 1) * CIN + c];
        float w2 = a.W_at[(4 * k4 + 2) * CIN + c], w3 = a.W_at[(4 * k4 + 3) * CIN + c];
#pragma unroll
        for (int q = 0; q < 8; q++) {
            float4 f = *(const float4*)&tmp[(h * 8 + q) * CIN + 4 * k4];
            acc2[q] += f.x * w0 + f.y * w1 + f.z * w2 + f.w * w3;
        }
    }
    for (int k4 = 0; k4 < CLAT / 4; k4++) {
        float w0 = a.W_lat[(4 * k4 + 0) * CIN + c], w1 = a.W_lat[(4 * k4 + 1) * CIN + c];
        float w2 = a.W_lat[(4 * k4 + 2) * CIN + c], w3 = a.W_lat[(4 * k4 + 3) * CIN + c];
#pragma unroll
        for (int q = 0; q < 8; q++) {
            float4 f = *(const float4*)&zs[(h * 8 + q) * CLAT + 4 * k4];
            acc2[q] += f.x * w0 + f.y * w1 + f.z * w2 + f.w * w3;
        }
    }
#pragma unroll
    for (int q = 0; q < 8; q++) {
        int nd = nb0 + h * 8 + q;
        a.s[(size_t)nd * CIN + c] = acc2[q];
        a.s_bf[(size_t)nd * CIN + c] = f2bs(acc2[q]);
    }
}

// ---------------- phase: init e tile (64 edges), sorted-order write ----------------------------
__device__ __forceinline__ void phase_init_e(const KArgs& a, char* smem, int tb, int tid)
{
    float* eas   = (float*)smem;            // 320
    float* tv    = (float*)(smem + 1280);   // 64
    int*   sp    = (int*)(smem + 1536);     // 64
    float* tmp   = (float*)(smem + 1792);   // 64*33
    float* wbt   = (float*)(smem + 10240);  // 1024
    float* wbond = (float*)(smem + 14336);  // 160
    float* cb    = (float*)(smem + 14976);
    float* wtb   = (float*)(smem + 15104);
    float* bbt2  = (float*)(smem + 15232);
    int k0 = tb * 64;
    for (int idx = tid; idx < 320; idx += 256) eas[idx] = a.ea[(size_t)k0 * 5 + idx];
    if (tid < 64) { tv[tid] = a.t[a.beg[k0 + tid]]; sp[tid] = a.invp[k0 + tid]; }
    for (int idx = tid; idx < 1024; idx += 256) wbt[idx] = a.W_bt[idx];
    if (tid < 160) wbond[tid] = a.W_bond[tid];
    if (tid < 32) { cb[tid] = a.b_bond[tid] + a.bt_b[tid]; wtb[tid] = a.Wt_b[tid]; bbt2[tid] = a.b_bt[tid]; }
    __syncthreads();
    int ch = tid & 31, eg = tid >> 5;
#pragma unroll
    for (int q = 0; q < 8; q++) {
        int le = eg * 8 + q;
        float acc = cb[ch] + tv[le] * wtb[ch];
#pragma unroll
        for (int bb = 0; bb < CNB; bb++) acc += eas[le * 5 + bb] * wbond[bb * 32 + ch];
        tmp[le * 33 + ch] = acc;
    }
    __syncthreads();
#pragma unroll
    for (int q = 0; q < 8; q++) {
        int le = eg * 8 + q;
        float acc2 = bbt2[ch];
        for (int d = 0; d < 32; d++) acc2 += tmp[le * 33 + d] * wbt[d * 32 + ch];
        size_t ix = (size_t)sp[le] * CED + ch;
        a.e[ix] = acc2;
        a.e_bf[ix] = f2bs(acc2);
        if (ch == 0) {
            int k = k0 + le;
            atomicMax(&a.map[(size_t)a.jj[k] * NN + a.ii[k]], k); // numpy last-write-wins
        }
    }
}

// ---------------- phase: node update + projections (16 nodes/tile); optional fused post --------
__device__ __forceinline__ void phase_node_proj(
    const KArgs& a, char* smem, int tile, int tid, bool DO_NODE, bool DO_POST,
    const short* Wpn_l, const float* bnode_l, const short* Wproj_slot)
{
    short* feat  = (short*)smem;            // 16*264 (aliased as feat_s2 in post phase)
    short* feat2 = (short*)(smem + 8448);   // 16*136
    int nb0 = tile * 16;
    int lane = tid & 63, w = tid >> 6;
    int quad = lane >> 4, n16 = lane & 15;

    if (DO_NODE) {
        { int kl = tid >> 4, c = tid & 15;
          *(uint4*)&feat[kl * 264 + c * 8] = ((const uint4*)a.s_bf)[(size_t)(nb0 + kl) * 16 + c]; }
        for (int idx = tid; idx < 16 * 32; idx += 256) {
            int kl = idx >> 5, c = idx & 31;
            size_t gix = (size_t)(nb0 + kl) * 32 + c;
            float4 v = ((const float4*)a.agg)[gix];
            ((float4*)a.agg)[gix] = (float4){0.f, 0.f, 0.f, 0.f};
            uint2 p; p.x = pack2(v.x, v.y); p.y = pack2(v.z, v.w);
            *(uint2*)&feat[kl * 264 + 128 + 4 * c] = p;
        }
        __syncthreads();
        f32x4 acc[2];
        acc[0] = (f32x4){0.f, 0.f, 0.f, 0.f};
        acc[1] = (f32x4){0.f, 0.f, 0.f, 0.f};
        const short* fbase = feat + n16 * 264 + quad * 8;
#pragma unroll
        for (int kt = 0; kt < 8; kt++) {
            bf16x8 av = *(const bf16x8*)(fbase + kt * 32);
#pragma unroll
            for (int n2 = 0; n2 < 2; n2++) {
                int nt = w * 2 + n2;
                bf16x8 b = *(const bf16x8*)(Wpn_l + ((size_t)(kt * 8 + nt) * 64 + lane) * 8);
                acc[n2] = __builtin_amdgcn_mfma_f32_16x16x32_bf16(av, b, acc[n2], 0, 0, 0);
            }
        }
#pragma unroll
        for (int n2 = 0; n2 < 2; n2++) {
            int col = (w * 2 + n2) * 16 + n16;
            float bb = bnode_l[col];
#pragma unroll
            for (int r = 0; r < 4; r++) {
                int row = quad * 4 + r;
                size_t ix = (size_t)(nb0 + row) * CIN + col;
                float v = a.s[ix] + silu_f(acc[n2][r] + bb);
                a.s[ix] = v;
                short bv = f2bs(v);
                a.s_bf[ix] = bv;
                feat2[row * 136 + col] = bv;
            }
        }
        __syncthreads();
    } else {
        int kl = tid >> 4, c = tid & 15;
        *(uint4*)&feat2[kl * 136 + c * 8] = ((const uint4*)a.s_bf)[(size_t)(nb0 + kl) * 16 + c];
        __syncthreads();
    }

    // projections: [U|V|P|Q] = s_new @ Wproj (K=128, N=320); wave w -> nt 5w..5w+4
    {
        f32x4 accp[5];
#pragma unroll
        for (int t2 = 0; t2 < 5; t2++) accp[t2] = (f32x4){0.f, 0.f, 0.f, 0.f};
        const short* abase = feat2 + n16 * 136 + quad * 8;
#pragma unroll
        for (int kt = 0; kt < 4; kt++) {
            bf16x8 av = *(const bf16x8*)(abase + kt * 32);
#pragma unroll
            for (int n5 = 0; n5 < 5; n5++) {
                int nt = w * 5 + n5;
                bf16x8 b = *(const bf16x8*)(Wproj_slot + ((size_t)(kt * 20 + nt) * 64 + lane) * 8);
                accp[n5] = __builtin_amdgcn_mfma_f32_16x16x32_bf16(av, b, accp[n5], 0, 0, 0);
            }
        }
#pragma unroll
        for (int n5 = 0; n5 < 5; n5++) {
            int nt = w * 5 + n5;
#pragma unroll
            for (int r = 0; r < 4; r++) {
                int node = tile * 16 + quad * 4 + r;
                float v = accp[n5][r];
                if (nt < 8)       a.U[(size_t)node * CIN + nt * 16 + n16] = v;
                else if (nt < 16) a.V[(size_t)node * CIN + (nt - 8) * 16 + n16] = v;
                else if (nt < 18) a.P[(size_t)node * CED + (nt - 16) * 16 + n16] = v;
                else              a.Q[(size_t)node * CED + (nt - 18) * 16 + n16] = v;
            }
        }
    }

    if (DO_POST) {
        // s2 = silu(s_new @ Wsh + bsh); al = s2 @ Wal + bal. feat region reused as feat_s2.
        short* feat_s2 = feat; // 16*136 shorts fits in dead feat region
        const short* fbase = feat2 + n16 * 136 + quad * 8;
        f32x4 acc[2];
        acc[0] = (f32x4){0.f, 0.f, 0.f, 0.f};
        acc[1] = (f32x4){0.f, 0.f, 0.f, 0.f};
#pragma unroll
        for (int kt = 0; kt < 4; kt++) {
            bf16x8 av = *(const bf16x8*)(fbase + kt * 32);
#pragma unroll
            for (int n2 = 0; n2 < 2; n2++) {
                int nt = w * 2 + n2;
                bf16x8 b = *(const bf16x8*)(a.Wpsh + ((size_t)(kt * 8 + nt) * 64 + lane) * 8);
                acc[n2] = __builtin_amdgcn_mfma_f32_16x16x32_bf16(av, b, acc[n2], 0, 0, 0);
            }
        }
#pragma unroll
        for (int n2 = 0; n2 < 2; n2++) {
            int col = (w * 2 + n2) * 16 + n16;
            float bb = a.bsh[col];
#pragma unroll
            for (int r = 0; r < 4; r++) {
                int row = quad * 4 + r;
                float v = silu_f(acc[n2][r] + bb);
                a.s2[(size_t)(nb0 + row) * CIN + col] = v;
                feat_s2[row * 136 + col] = f2bs(v);
            }
        }
        __syncthreads();
        const short* abase2 = feat_s2 + n16 * 136 + quad * 8;
        f32x4 acca[2];
        acca[0] = (f32x4){0.f, 0.f, 0.f, 0.f};
        acca[1] = (f32x4){0.f, 0.f, 0.f, 0.f};
        int nAl = (w == 0) ? 2 : 1;
        int ntl[2] = {w, 4};
#pragma unroll
        for (int kt = 0; kt < 4; kt++) {
            bf16x8 av = *(const bf16x8*)(abase2 + kt * 32);
#pragma unroll
            for (int q = 0; q < 2; q++) {
                if (q < nAl) {
                    bf16x8 b = *(const bf16x8*)(a.Wpal + ((size_t)(kt * 5 + ntl[q]) * 64 + lane) * 8);
                    acca[q] = __builtin_amdgcn_mfma_f32_16x16x32_bf16(av, b, acca[q], 0, 0, 0);
                }
            }
        }
#pragma unroll
        for (int q = 0; q < 2; q++) {
            if (q < nAl) {
                int col = ntl[q] * 16 + n16;
                float bb = a.bal[col];
#pragma unroll
                for (int r = 0; r < 4; r++) {
                    int node = nb0 + quad * 4 + r;
                    float v = acca[q][r] + bb;
                    if (col < CFA) a.out[OFF_AT + node * CFA + col] = v;
                    else           a.out[(size_t)node * CLAT + (col - CFA)] = v;
                }
            }
        }
    }
}

// ---------------- phase: per-edge tile (64 sorted edges); bf16 uv/pq ---------------------------
// LDS: feat_e 5120 | uv_bf 17408 | pq_bf 5120 | sii 256 | sjj 256 = 28160 B -> 5 blocks/CU
__device__ __forceinline__ void phase_em(
    const KArgs& a, char* smem, int tb, int tid, bool DO_EDGE, bool DO_MSG,
    const short* We3p, const float* bedge_l, const short* W3mp, const float* bmsg_l)
{
    short* feat_e = (short*)smem;             // 64*40 bf16
    short* uv_bf  = (short*)(smem + 5120);    // 64*136 bf16 (U[i]+V[j]; then m values)
    short* pq_bf  = (short*)(smem + 22528);   // 64*40 bf16 (P[i]+Q[j])
    int*   sii    = (int*)(smem + 27648);     // 64
    int*   sjj    = (int*)(smem + 27904);     // 64
    int e0 = tb * 64;
    if (tid < 64) sii[tid] = a.i_s[e0 + tid];
    else if (tid < 128) sjj[tid - 64] = a.j_s[e0 + tid - 64];
    __syncthreads();
    { int kl = tid >> 2, c = tid & 3;
      uint4 v = ((const uint4*)a.e_bf)[(size_t)e0 * 4 + tid];
      *(uint4*)&feat_e[kl * 40 + c * 8] = v; }
    if (DO_EDGE) {
        for (int idx = tid; idx < 64 * 8; idx += 256) {
            int kl = idx >> 3, c = idx & 7;
            float4 av = ((const float4*)a.P)[(size_t)sii[kl] * 8 + c];
            float4 bv = ((const float4*)a.Q)[(size_t)sjj[kl] * 8 + c];
            uint2 p; p.x = pack2(av.x + bv.x, av.y + bv.y); p.y = pack2(av.z + bv.z, av.w + bv.w);
            *(uint2*)&pq_bf[kl * 40 + 4 * c] = p;
        }
    }
    if (DO_MSG) {
        for (int idx = tid; idx < 64 * 32; idx += 256) {
            int kl = idx >> 5, c = idx & 31;
            float4 av = ((const float4*)a.U)[(size_t)sii[kl] * 32 + c];
            float4 bv = ((const float4*)a.V)[(size_t)sjj[kl] * 32 + c];
            uint2 p; p.x = pack2(av.x + bv.x, av.y + bv.y); p.y = pack2(av.z + bv.z, av.w + bv.w);
            *(uint2*)&uv_bf[kl * 136 + 4 * c] = p;
        }
    }
    __syncthreads();
    int lane = tid & 63, w = tid >> 6;
    int quad = lane >> 4, n16 = lane & 15;
    const short* abase = feat_e + (w * 16 + n16) * 40 + quad * 8;
    bf16x8 av = *(const bf16x8*)abase;

    if (DO_EDGE) {
        f32x4 acc_e[2];
        acc_e[0] = (f32x4){0.f, 0.f, 0.f, 0.f};
        acc_e[1] = (f32x4){0.f, 0.f, 0.f, 0.f};
#pragma unroll
        for (int nt = 0; nt < 2; nt++) {
            bf16x8 b = *(const bf16x8*)(We3p + ((size_t)(nt * 64 + lane)) * 8);
            acc_e[nt] = __builtin_amdgcn_mfma_f32_16x16x32_bf16(av, b, acc_e[nt], 0, 0, 0);
        }
#pragma unroll
        for (int nt = 0; nt < 2; nt++) {
            int ch = nt * 16 + n16;
            float bb = bedge_l[ch];
#pragma unroll
            for (int r = 0; r < 4; r++) {
                int el = w * 16 + quad * 4 + r;
                size_t ix = (size_t)(e0 + el) * CED + ch;
                float v = a.e[ix] + silu_f(acc_e[nt][r] + bb + bs2f(pq_bf[el * 40 + ch]));
                a.e[ix] = v;
                short bv = f2bs(v);
                a.e_bf[ix] = bv;
                feat_e[el * 40 + ch] = bv;
            }
        }
        av = *(const bf16x8*)abase; // re-read own-wave patched row
    }

    if (DO_MSG) {
        f32x4 acc_m[8];
#pragma unroll
        for (int t2 = 0; t2 < 8; t2++) acc_m[t2] = (f32x4){0.f, 0.f, 0.f, 0.f};
#pragma unroll
        for (int nt = 0; nt < 8; nt++) {
            bf16x8 b = *(const bf16x8*)(W3mp + ((size_t)(nt * 64 + lane)) * 8);
            acc_m[nt] = __builtin_amdgcn_mfma_f32_16x16x32_bf16(av, b, acc_m[nt], 0, 0, 0);
        }
#pragma unroll
        for (int nt = 0; nt < 8; nt++) {
            int ch = nt * 16 + n16;
            float bb = bmsg_l[ch];
#pragma unroll
            for (int r = 0; r < 4; r++) {
                int el = w * 16 + quad * 4 + r;
                int lix = el * 136 + ch;
                float m = silu_f(acc_m[nt][r] + bb + bs2f(uv_bf[lix])); // (el,ch) owner thread
                uv_bf[lix] = f2bs(m);
            }
        }
        __syncthreads();
        if (tid < 128) { // group-reduce by sorted target; fp32 running sum
            int c = tid;
            float run = 0.f;
            int cur = sii[0];
            for (int r = 0; r < 64; r++) {
                int tg = sii[r];
                if (tg != cur) { atomicAdd(&a.agg[(size_t)cur * CIN + c], run); run = 0.f; cur = tg; }
                run += bs2f(uv_bf[r * 136 + c]);
            }
            atomicAdd(&a.agg[(size_t)cur * CIN + c], run);
        }
    }
}

// ---------------- phase: post edge tile (64 edges, original order) -----------------------------
__device__ __forceinline__ void phase_post_edge(const KArgs& a, char* smem, int tb, int tid)
{
    short* esym  = (short*)smem;             // 64*40
    float* sbias = (float*)(smem + 5120);    // 64*132, aliased as fshT
    int* sii = (int*)(smem + 38912);
    int* sjj = (int*)(smem + 39168);
    int* skf = (int*)(smem + 39424);
    int* skb = (int*)(smem + 39680);
    int e0 = tb * 64;
    if (tid < 64) sii[tid] = a.ii[e0 + tid];
    else if (tid < 128) sjj[tid - 64] = a.jj[e0 + tid - 64];
    __syncthreads();
    if (tid < 64) skf[tid] = a.invp[a.map[(size_t)sjj[tid] * NN + sii[tid]]];
    else if (tid < 128) {
        int m = a.map[(size_t)sii[tid - 64] * NN + sjj[tid - 64]];
        skb[tid - 64] = (m >= 0) ? a.invp[m] : -1;
    }
    __syncthreads();
    for (int idx = tid; idx < 64 * 8; idx += 256) {
        int kl = idx >> 3, c = idx & 7;
        float4 av = ((const float4*)a.e)[(size_t)skf[kl] * 8 + c];
        int kb = skb[kl];
        float4 bv = {0.f, 0.f, 0.f, 0.f};
        if (kb >= 0) bv = ((const float4*)a.e)[(size_t)kb * 8 + c];
        uint2 p; p.x = pack2(0.5f * (av.x + bv.x), 0.5f * (av.y + bv.y));
        p.y = pack2(0.5f * (av.z + bv.z), 0.5f * (av.w + bv.w));
        *(uint2*)&esym[kl * 40 + 4 * c] = p;
    }
    for (int idx = tid; idx < 64 * 32; idx += 256) {
        int kl = idx >> 5, c = idx & 31;
        float4 av = ((const float4*)a.s2)[(size_t)sii[kl] * 32 + c];
        float4 bv = ((const float4*)a.s2)[(size_t)sjj[kl] * 32 + c];
        *(float4*)&sbias[kl * 132 + 4 * c] = (float4){av.x + bv.x, av.y + bv.y, av.z + bv.z, av.w + bv.w};
    }
    __syncthreads();
    int lane = tid & 63, w = tid >> 6;
    int quad = lane >> 4, n16 = lane & 15;
    bf16x8 av = *(const bf16x8*)(esym + (w * 16 + n16) * 40 + quad * 8);
    f32x4 acc[8];
#pragma unroll
    for (int nt = 0; nt < 8; nt++) {
        bf16x8 b = *(const bf16x8*)(a.Wpbm + ((size_t)nt * 64 + lane) * 8);
        f32x4 zero = {0.f, 0.f, 0.f, 0.f};
        acc[nt] = __builtin_amdgcn_mfma_f32_16x16x32_bf16(av, b, zero, 0, 0, 0);
    }
    float f[8][4];
#pragma unroll
    for (int nt = 0; nt < 8; nt++) {
        int col = nt * 16 + n16;
        float bb = a.bbm[col];
#pragma unroll
        for (int r = 0; r < 4; r++) {
            int row = w * 16 + quad * 4 + r;
            f[nt][r] = silu_f(acc[nt][r] + bb + sbias[row * 132 + col]);
        }
    }
    __syncthreads();
    float* fshT = sbias; // [128][66]
#pragma unroll
    for (int nt = 0; nt < 8; nt++) {
        int col = nt * 16 + n16;
#pragma unroll
        for (int r = 0; r < 4; r++) {
            int row = w * 16 + quad * 4 + r;
            fshT[col * 66 + row] = f[nt][r];
        }
    }
    __syncthreads();
    for (int idx = tid; idx < 64 * CNB; idx += 256) {
        int kl = idx / CNB, b = idx - kl * CNB;
        float acc3 = a.bbl[b];
        for (int d = 0; d < CIN; d++) acc3 += fshT[d * 66 + kl] * a.Wbl[d * CNB + b];
        a.out[OFF_B + (size_t)(e0 + kl) * CNB + b] = acc3;
    }
}

// ---------------- kernels ----------------------------------------------------------------------
__global__ __launch_bounds__(256) void k_prologue(KArgs a)
{
    __shared__ __align__(16) char smem[13440];
    int b = blockIdx.x, tid = threadIdx.x;
    if (b < 960) phase_pack(a, b * 256 + tid, 960 * 256);
    else if (b < 1088) phase_init_s(a, smem, b - 960, tid);
    else {
        int base = (b - 1088) * 1024;
#pragma unroll
        for (int q = 0; q < 4; q++) atomicAdd(&a.cnt[a.ii[base + q * 256 + tid]], 1);
    }
}
__global__ __launch_bounds__(256) void k_prefix(KArgs a)
{
    __shared__ int part[256];
    int tid = threadIdx.x;
    int loc[8], sum = 0;
#pragma unroll
    for (int q = 0; q < 8; q++) { loc[q] = a.cnt[tid * 8 + q]; sum += loc[q]; }
    part[tid] = sum;
    __syncthreads();
    if (tid == 0) { int r = 0; for (int i = 0; i < 256; i++) { int v = part[i]; part[i] = r; r += v; } }
    __syncthreads();
    int r = part[tid];
#pragma unroll
    for (int q = 0; q < 8; q++) { a.rowpos[tid * 8 + q] = r; r += loc[q]; }
}
__global__ void k_perm(KArgs a)
{
    int k = blockIdx.x * 256 + threadIdx.x;
    int iv = a.ii[k];
    int p = atomicAdd(&a.rowpos[iv], 1);
    a.invp[k] = p;
    a.i_s[p] = iv;
    a.j_s[p] = a.jj[k];
}
__global__ __launch_bounds__(256) void k_init_e(KArgs a)
{
    __shared__ __align__(16) char smem[15360];
    phase_init_e(a, smem, blockIdx.x, threadIdx.x);
}
__global__ __launch_bounds__(256) void k_node_proj(KArgs a, int donode, int dopost,
                                                   const short* Wpn_l, const float* bnode_l,
                                                   const short* Wproj_slot)
{
    __shared__ __align__(16) char smem[12800];
    phase_node_proj(a, smem, blockIdx.x, threadIdx.x, donode != 0, dopost != 0,
                    Wpn_l, bnode_l, Wproj_slot);
}
__global__ __launch_bounds__(256) void k_em(KArgs a, int de, int dm, const short* We3p,
                                            const float* bedge_l, const short* W3mp, const float* bmsg_l)
{
    __shared__ __align__(16) char smem[28160]; // 5 blocks/CU
    phase_em(a, smem, blockIdx.x, threadIdx.x, de != 0, dm != 0, We3p, bedge_l, W3mp, bmsg_l);
}
__global__ __launch_bounds__(256) void k_post_edge(KArgs a)
{
    __shared__ __align__(16) char smem[39936];
    phase_post_edge(a, smem, blockIdx.x, threadIdx.x);
}

extern "C" void kernel_launch(void* const* d_in, const int* in_sizes, int n_in,
                              void* d_out, int out_size, void* d_ws, size_t ws_size,
                              hipStream_t stream) {
    KArgs a;
    a.x      = (const float*)d_in[0];
    a.t      = (const float*)d_in[1];
    a.z      = (const float*)d_in[2];
    const int* eidx = (const int*)d_in[3];
    a.jj     = eidx;        // edge_index[0] = j
    a.ii     = eidx + NE;   // edge_index[1] = i
    a.ea     = (const float*)d_in[4];
    a.batch  = (const int*)d_in[5];
    a.beg    = (const int*)d_in[6];
    a.Wt_a   = (const float*)d_in[7];
    a.bt_a   = (const float*)d_in[8];
    a.Wt_b   = (const float*)d_in[9];
    a.bt_b   = (const float*)d_in[10];
    a.W_atom = (const float*)d_in[11];
    a.b_atom = (const float*)d_in[12];
    a.W_bond = (const float*)d_in[13];
    a.b_bond = (const float*)d_in[14];
    a.W_lat  = (const float*)d_in[15];
    a.b_lat  = (const float*)d_in[16];
    a.W_at   = (const float*)d_in[17];
    a.b_at   = (const float*)d_in[18];
    a.W_bt   = (const float*)d_in[19];
    a.b_bt   = (const float*)d_in[20];
    a.Wmsg   = (const float*)d_in[21];
    a.bmsg   = (const float*)d_in[22];
    a.Wnode  = (const float*)d_in[23];
    a.bnode  = (const float*)d_in[24];
    a.Wedge  = (const float*)d_in[25];
    a.bedge  = (const float*)d_in[26];
    a.Wsh    = (const float*)d_in[27];
    a.bsh    = (const float*)d_in[28];
    a.Wbm    = (const float*)d_in[29];
    a.bbm    = (const float*)d_in[30];
    a.Wbl    = (const float*)d_in[31];
    a.bbl    = (const float*)d_in[32];
    a.Wal    = (const float*)d_in[33];
    a.bal    = (const float*)d_in[34];

    a.s      = (float*)d_ws;
    a.e      = a.s + (size_t)NN * CIN;
    a.agg    = a.e + (size_t)NE * CED;
    a.cnt    = (int*)(a.agg + (size_t)NN * CIN);
    a.rowpos = a.cnt + NN;
    a.invp   = a.rowpos + NN;
    a.i_s    = a.invp + NE;
    a.j_s    = a.i_s + NE;
    a.s2     = (float*)(a.j_s + NE);
    a.U      = a.s2 + (size_t)NN * CIN;
    a.V      = a.U + (size_t)NN * CIN;
    a.P      = a.V + (size_t)NN * CIN;
    a.Q      = a.P + (size_t)NN * CED;
    a.map    = (int*)(a.Q + (size_t)NN * CED);
    a.s_bf   = (short*)(a.map + (size_t)NN * NN);
    a.e_bf   = a.s_bf + (size_t)NN * CIN;
    a.Wpn    = a.e_bf + (size_t)NE * CED;
    a.Wpsh   = a.Wpn + (size_t)NL * 8 * 8 * 64 * 8;
    a.Wpal   = a.Wpsh + (size_t)4 * 8 * 64 * 8;
    a.Wpbm   = a.Wpal + (size_t)4 * 5 * 64 * 8;
    a.Wproj  = a.Wpbm + (size_t)8 * 64 * 8;
    a.W3m    = a.Wproj + (size_t)6 * 4 * 20 * 64 * 8;
    a.We3    = a.W3m + (size_t)NL * 8 * 64 * 8;
    a.out    = (float*)d_out;

    hipMemsetAsync(a.map, 0xFF, (size_t)NN * NN * sizeof(int), stream);
    hipMemsetAsync(a.agg, 0, ((size_t)NN * CIN + NN) * sizeof(float), stream); // agg + cnt

    k_prologue<<<1152, 256, 0, stream>>>(a);
    k_prefix<<<1, 256, 0, stream>>>(a);
    k_perm<<<NE / 256, 256, 0, stream>>>(a);
    k_init_e<<<NE / 64, 256, 0, stream>>>(a);
    k_node_proj<<<NN / 16, 256, 0, stream>>>(a, 0, 0, nullptr, nullptr, a.Wproj);
    k_em<<<NE / 64, 256, 0, stream>>>(a, 0, 1, nullptr, nullptr, a.W3m, a.bmsg);
    for (int l = 0; l < NL; l++) {
        int dopost = (l == NL - 1) ? 1 : 0; // fuse post-node into last node update
        k_node_proj<<<NN / 16, 256, 0, stream>>>(a, 1, dopost,
            a.Wpn + (size_t)l * 8 * 8 * 64 * 8, a.bnode + l * CIN,
            a.Wproj + (size_t)(l + 1) * 4 * 20 * 64 * 8);
        int dm = (l < NL - 1) ? 1 : 0;
        k_em<<<NE / 64, 256, 0, stream>>>(a, 1, dm,
            a.We3 + (size_t)l * 2 * 64 * 8, a.bedge + l * CED,
            dm ? a.W3m + (size_t)(l + 1) * 8 * 64 * 8 : a.W3m,
            dm ? a.bmsg + (l + 1) * CIN : a.bmsg);
    }
    k_post_edge<<<NE / 64, 256, 0, stream>>>(a);
}